// Round 1
// baseline (135.965 us; speedup 1.0000x reference)
//
#include <hip/hip_runtime.h>
#include <math.h>

// ChamferLoss: target [B,M,2] f32, actual [B,N,2] f32
// out = concat(forward[B,M], backward[B,N]) f32
//   forward[b,m] = min_n ||t[b,m]-a[b,n]||
//   backward[b,n] = min_m ||t[b,m]-a[b,n]||
//
// Strategy: VALU-bound brute force. Each thread owns TM query points and
// scans all refs with wave-uniform (scalar-load) addressing. Min over
// (|a|^2 - 2 q.a), add |q|^2 at the end, clamp, one sqrt per output.

#define BLK 256
#define TM  2
#define UN  8

__global__ __launch_bounds__(BLK) void chamfer_min_kernel(
    const float2* __restrict__ tpts,   // [B, M]
    const float2* __restrict__ apts,   // [B, N]
    float* __restrict__ out,           // [B*M + B*N]
    int M, int N, int B)
{
    const int b   = blockIdx.y;
    const int dir = blockIdx.z;   // 0: forward (queries=target), 1: backward

    const float2* __restrict__ Q = dir ? apts : tpts;
    const float2* __restrict__ R = dir ? tpts : apts;
    const int NQ = dir ? N : M;
    const int NR = dir ? M : N;
    float* __restrict__ o = out + (dir ? ((size_t)B * M + (size_t)b * N)
                                       : ((size_t)b * M));

    const float2* __restrict__ q = Q + (size_t)b * NQ;
    const float2* __restrict__ r = R + (size_t)b * NR;

    int   qi[TM];
    float qx[TM], qy[TM], qn[TM], mn[TM];
#pragma unroll
    for (int k = 0; k < TM; ++k) {
        qi[k] = blockIdx.x * (BLK * TM) + k * BLK + (int)threadIdx.x;
        int idx = qi[k] < NQ ? qi[k] : NQ - 1;
        float2 p = q[idx];
        qx[k] = p.x; qy[k] = p.y;
        qn[k] = fmaf(p.y, p.y, p.x * p.x);
        mn[k] = 3.0e38f;
    }

    // NR is a multiple of UN for this problem (4096 % 8 == 0).
    for (int n = 0; n < NR; n += UN) {
        float vx[UN], vy[UN], va[UN];
#pragma unroll
        for (int j = 0; j < UN; ++j) {
            float2 p = r[n + j];          // wave-uniform -> scalar loads
            vx[j] = p.x; vy[j] = p.y;
            va[j] = fmaf(p.y, p.y, p.x * p.x);
        }
#pragma unroll
        for (int k = 0; k < TM; ++k) {
            float v[UN];
#pragma unroll
            for (int j = 0; j < UN; ++j) {
                float s = fmaf(qy[k], vy[j], qx[k] * vx[j]);
                v[j] = fmaf(-2.0f, s, va[j]);   // |a|^2 - 2 q.a
            }
            float m01 = fminf(v[0], v[1]);
            float m23 = fminf(v[2], v[3]);
            float m45 = fminf(v[4], v[5]);
            float m67 = fminf(v[6], v[7]);
            float m = fminf(fminf(m01, m23), fminf(m45, m67));
            mn[k] = fminf(mn[k], m);
        }
    }

#pragma unroll
    for (int k = 0; k < TM; ++k) {
        if (qi[k] < NQ) {
            float d2 = fmaxf(mn[k] + qn[k], 0.0f);
            o[qi[k]] = sqrtf(d2);
        }
    }
}

extern "C" void kernel_launch(void* const* d_in, const int* in_sizes, int n_in,
                              void* d_out, int out_size, void* d_ws, size_t ws_size,
                              hipStream_t stream) {
    const float2* tpts = (const float2*)d_in[0];
    const float2* apts = (const float2*)d_in[1];
    float* out = (float*)d_out;

    const int B = 16;
    const int M = in_sizes[0] / (B * 2);
    const int N = in_sizes[1] / (B * 2);

    const int maxQ = M > N ? M : N;
    dim3 grid((maxQ + BLK * TM - 1) / (BLK * TM), B, 2);
    dim3 block(BLK);
    chamfer_min_kernel<<<grid, block, 0, stream>>>(tpts, apts, out, M, N, B);
}

// Round 2
// 51.547 us; speedup vs baseline: 2.6377x; 2.6377x over previous
//
#include <hip/hip_runtime.h>
#include <math.h>

// ChamferLoss: target [B,M,2] f32, actual [B,N,2] f32
// out = concat(forward[B,M], backward[B,N]) f32
//
// Round 2: fix occupancy (11% -> ~50%) by splitting the reference dim into
// RC chunks per (b,dir) and combining partial minima via atomicMin on
// uint-encoded d^2 (non-negative float bits are order-preserving).
// Math per pair: v = fma(-2qx, x, fma(-2qy, y, |a|^2))  -> 2 fma
// plus amortized |a|^2 (0.25 @ TM=8) and v_min3-shaped min tree (0.5).

#define BLK 256
#define TM  8     // queries per thread
#define RC  16    // reference chunks per (b,dir)
#define UNR 4     // refs per inner iteration

__global__ __launch_bounds__(256) void chamfer_init(unsigned int* __restrict__ out, int n) {
    int i = blockIdx.x * 256 + threadIdx.x;
    if (i < n) out[i] = 0x7F800000u;  // +inf
}

__global__ __launch_bounds__(BLK) void chamfer_partial(
    const float2* __restrict__ tpts,   // [B, M]
    const float2* __restrict__ apts,   // [B, N]
    unsigned int* __restrict__ out,    // [B*M + B*N], d^2 as uint bits
    int M, int N, int B)
{
    const int b   = blockIdx.y;
    const int zc  = blockIdx.z;
    const int dir = zc & 1;       // 0: forward (queries=target), 1: backward
    const int rc  = zc >> 1;      // which reference chunk

    const float2* __restrict__ Q = dir ? apts : tpts;
    const float2* __restrict__ R = dir ? tpts : apts;
    const int NQ = dir ? N : M;
    const int NR = dir ? M : N;
    unsigned int* __restrict__ o =
        out + (dir ? ((size_t)B * M + (size_t)b * N) : ((size_t)b * M));

    const float2* __restrict__ q = Q + (size_t)b * NQ;
    const float2* __restrict__ r = R + (size_t)b * NR;

    // this block's reference chunk
    const int clen = (NR + RC - 1) / RC;
    const int rbeg = rc * clen;
    const int rend = (rbeg + clen < NR) ? (rbeg + clen) : NR;
    if (rbeg >= rend) return;

    int   qi[TM];
    float n2x[TM], n2y[TM], qn[TM], mn[TM];
#pragma unroll
    for (int k = 0; k < TM; ++k) {
        qi[k] = blockIdx.x * (BLK * TM) + k * BLK + (int)threadIdx.x;
        int idx = qi[k] < NQ ? qi[k] : NQ - 1;
        float2 p = q[idx];
        n2x[k] = -2.0f * p.x;
        n2y[k] = -2.0f * p.y;
        qn[k]  = fmaf(p.y, p.y, p.x * p.x);
        mn[k]  = 3.0e38f;
    }

    int n = rbeg;
    // main unrolled loop (clen is 256 here; handle generically anyway)
    for (; n + UNR <= rend; n += UNR) {
        float vx[UNR], vy[UNR], va[UNR];
#pragma unroll
        for (int j = 0; j < UNR; ++j) {
            float2 p = r[n + j];              // wave-uniform -> scalar loads
            vx[j] = p.x; vy[j] = p.y;
            va[j] = fmaf(p.y, p.y, p.x * p.x);
        }
#pragma unroll
        for (int k = 0; k < TM; ++k) {
            float v0 = fmaf(n2x[k], vx[0], fmaf(n2y[k], vy[0], va[0]));
            float v1 = fmaf(n2x[k], vx[1], fmaf(n2y[k], vy[1], va[1]));
            float v2 = fmaf(n2x[k], vx[2], fmaf(n2y[k], vy[2], va[2]));
            float v3 = fmaf(n2x[k], vx[3], fmaf(n2y[k], vy[3], va[3]));
            float t  = fminf(fminf(v0, v1), v2);      // -> v_min3
            mn[k]    = fminf(fminf(t, v3), mn[k]);    // -> v_min3
        }
    }
    for (; n < rend; ++n) {
        float2 p = r[n];
        float va = fmaf(p.y, p.y, p.x * p.x);
#pragma unroll
        for (int k = 0; k < TM; ++k) {
            float v = fmaf(n2x[k], p.x, fmaf(n2y[k], p.y, va));
            mn[k] = fminf(mn[k], v);
        }
    }

#pragma unroll
    for (int k = 0; k < TM; ++k) {
        if (qi[k] < NQ) {
            float d2 = fmaxf(mn[k] + qn[k], 0.0f);
            atomicMin(&o[qi[k]], __float_as_uint(d2));
        }
    }
}

__global__ __launch_bounds__(256) void chamfer_sqrt(
    unsigned int* __restrict__ io, int n)
{
    int i = blockIdx.x * 256 + threadIdx.x;
    if (i < n) {
        float d2 = __uint_as_float(io[i]);
        ((float*)io)[i] = sqrtf(d2);
    }
}

extern "C" void kernel_launch(void* const* d_in, const int* in_sizes, int n_in,
                              void* d_out, int out_size, void* d_ws, size_t ws_size,
                              hipStream_t stream) {
    const float2* tpts = (const float2*)d_in[0];
    const float2* apts = (const float2*)d_in[1];
    unsigned int* out = (unsigned int*)d_out;

    const int B = 16;
    const int M = in_sizes[0] / (B * 2);
    const int N = in_sizes[1] / (B * 2);
    const int total = B * (M + N);

    chamfer_init<<<(total + 255) / 256, 256, 0, stream>>>(out, total);

    const int maxQ = M > N ? M : N;
    dim3 grid((maxQ + BLK * TM - 1) / (BLK * TM), B, 2 * RC);
    chamfer_partial<<<grid, dim3(BLK), 0, stream>>>(tpts, apts, out, M, N, B);

    chamfer_sqrt<<<(total + 255) / 256, 256, 0, stream>>>(out, total);
}

// Round 3
// 49.007 us; speedup vs baseline: 2.7744x; 1.0518x over previous
//
#include <hip/hip_runtime.h>
#include <math.h>

// ChamferLoss: target [B,M,2] f32, actual [B,N,2] f32
// out = concat(forward[B,M], backward[B,N]) f32
//
// Round 3: RC 16->32 => 2048 blocks = 8 blocks/CU x 4 waves = 32 waves/CU
// (100% occupancy at VGPR=28). Same math as round 2: partial minima over
// reference chunks combined via atomicMin on uint-encoded d^2 (non-negative
// float bits are order-preserving; min is commutative -> deterministic).
// Per pair: v = fma(-2qx, x, fma(-2qy, y, |a|^2)) -> 2 fma; |a|^2 amortized
// over TM=8 queries; min tree shaped for v_min3 fusion.

#define BLK 256
#define TM  8     // queries per thread
#define RC  32    // reference chunks per (b,dir)
#define UNR 4     // refs per inner iteration

__global__ __launch_bounds__(256) void chamfer_init(unsigned int* __restrict__ out, int n) {
    int i = blockIdx.x * 256 + threadIdx.x;
    if (i < n) out[i] = 0x7F800000u;  // +inf
}

__global__ __launch_bounds__(BLK) void chamfer_partial(
    const float2* __restrict__ tpts,   // [B, M]
    const float2* __restrict__ apts,   // [B, N]
    unsigned int* __restrict__ out,    // [B*M + B*N], d^2 as uint bits
    int M, int N, int B)
{
    const int b   = blockIdx.y;
    const int zc  = blockIdx.z;
    const int dir = zc & 1;       // 0: forward (queries=target), 1: backward
    const int rc  = zc >> 1;      // which reference chunk

    const float2* __restrict__ Q = dir ? apts : tpts;
    const float2* __restrict__ R = dir ? tpts : apts;
    const int NQ = dir ? N : M;
    const int NR = dir ? M : N;
    unsigned int* __restrict__ o =
        out + (dir ? ((size_t)B * M + (size_t)b * N) : ((size_t)b * M));

    const float2* __restrict__ q = Q + (size_t)b * NQ;
    const float2* __restrict__ r = R + (size_t)b * NR;

    // this block's reference chunk
    const int clen = (NR + RC - 1) / RC;
    const int rbeg = rc * clen;
    const int rend = (rbeg + clen < NR) ? (rbeg + clen) : NR;
    if (rbeg >= rend) return;

    int   qi[TM];
    float n2x[TM], n2y[TM], qn[TM], mn[TM];
#pragma unroll
    for (int k = 0; k < TM; ++k) {
        qi[k] = blockIdx.x * (BLK * TM) + k * BLK + (int)threadIdx.x;
        int idx = qi[k] < NQ ? qi[k] : NQ - 1;
        float2 p = q[idx];
        n2x[k] = -2.0f * p.x;
        n2y[k] = -2.0f * p.y;
        qn[k]  = fmaf(p.y, p.y, p.x * p.x);
        mn[k]  = 3.0e38f;
    }

    int n = rbeg;
    for (; n + UNR <= rend; n += UNR) {
        float vx[UNR], vy[UNR], va[UNR];
#pragma unroll
        for (int j = 0; j < UNR; ++j) {
            float2 p = r[n + j];              // wave-uniform -> scalar loads
            vx[j] = p.x; vy[j] = p.y;
            va[j] = fmaf(p.y, p.y, p.x * p.x);
        }
#pragma unroll
        for (int k = 0; k < TM; ++k) {
            float v0 = fmaf(n2x[k], vx[0], fmaf(n2y[k], vy[0], va[0]));
            float v1 = fmaf(n2x[k], vx[1], fmaf(n2y[k], vy[1], va[1]));
            float v2 = fmaf(n2x[k], vx[2], fmaf(n2y[k], vy[2], va[2]));
            float v3 = fmaf(n2x[k], vx[3], fmaf(n2y[k], vy[3], va[3]));
            float t  = fminf(fminf(v0, v1), v2);      // -> v_min3
            mn[k]    = fminf(fminf(t, v3), mn[k]);    // -> v_min3
        }
    }
    for (; n < rend; ++n) {
        float2 p = r[n];
        float va = fmaf(p.y, p.y, p.x * p.x);
#pragma unroll
        for (int k = 0; k < TM; ++k) {
            float v = fmaf(n2x[k], p.x, fmaf(n2y[k], p.y, va));
            mn[k] = fminf(mn[k], v);
        }
    }

#pragma unroll
    for (int k = 0; k < TM; ++k) {
        if (qi[k] < NQ) {
            float d2 = fmaxf(mn[k] + qn[k], 0.0f);
            atomicMin(&o[qi[k]], __float_as_uint(d2));
        }
    }
}

__global__ __launch_bounds__(256) void chamfer_sqrt(
    unsigned int* __restrict__ io, int n)
{
    int i = blockIdx.x * 256 + threadIdx.x;
    if (i < n) {
        float d2 = __uint_as_float(io[i]);
        ((float*)io)[i] = sqrtf(d2);
    }
}

extern "C" void kernel_launch(void* const* d_in, const int* in_sizes, int n_in,
                              void* d_out, int out_size, void* d_ws, size_t ws_size,
                              hipStream_t stream) {
    const float2* tpts = (const float2*)d_in[0];
    const float2* apts = (const float2*)d_in[1];
    unsigned int* out = (unsigned int*)d_out;

    const int B = 16;
    const int M = in_sizes[0] / (B * 2);
    const int N = in_sizes[1] / (B * 2);
    const int total = B * (M + N);

    chamfer_init<<<(total + 255) / 256, 256, 0, stream>>>(out, total);

    const int maxQ = M > N ? M : N;
    dim3 grid((maxQ + BLK * TM - 1) / (BLK * TM), B, 2 * RC);
    chamfer_partial<<<grid, dim3(BLK), 0, stream>>>(tpts, apts, out, M, N, B);

    chamfer_sqrt<<<(total + 255) / 256, 256, 0, stream>>>(out, total);
}

// Round 4
// 43.363 us; speedup vs baseline: 3.1355x; 1.1302x over previous
//
#include <hip/hip_runtime.h>
#include <math.h>

// ChamferLoss: target [B,M,2] f32, actual [B,N,2] f32
// out = concat(forward[B,M], backward[B,N]) f32
//
// Round 4: packed FP32 (VOP3P v_pk_fma_f32 / v_pk_min_f32) via
// <2 x float> ext_vector + __builtin_elementwise_*: 2 refs per lane-inst.
// Per query per 2 refs: 2 pk_fma + 1 pk_min  -> 1.5 inst/pair (was ~3).
// Partial minima over RC=32 reference chunks, combined with atomicMin on
// uint-encoded d^2 (non-negative float bits order-preserving, min
// commutative -> deterministic under graph replay).

typedef float f32x2 __attribute__((ext_vector_type(2)));

#define BLK 256
#define TM  8     // queries per thread
#define RC  32    // reference chunks per (b,dir)

__global__ __launch_bounds__(256) void chamfer_init(unsigned int* __restrict__ out, int n) {
    int i = blockIdx.x * 256 + threadIdx.x;
    if (i < n) out[i] = 0x7F800000u;  // +inf
}

__global__ __launch_bounds__(BLK) void chamfer_partial(
    const float2* __restrict__ tpts,   // [B, M]
    const float2* __restrict__ apts,   // [B, N]
    unsigned int* __restrict__ out,    // [B*M + B*N], d^2 as uint bits
    int M, int N, int B)
{
    const int b   = blockIdx.y;
    const int zc  = blockIdx.z;
    const int dir = zc & 1;       // 0: forward (queries=target), 1: backward
    const int rc  = zc >> 1;      // which reference chunk

    const float2* __restrict__ Q = dir ? apts : tpts;
    const float2* __restrict__ R = dir ? tpts : apts;
    const int NQ = dir ? N : M;
    const int NR = dir ? M : N;
    unsigned int* __restrict__ o =
        out + (dir ? ((size_t)B * M + (size_t)b * N) : ((size_t)b * M));

    const float2* __restrict__ q = Q + (size_t)b * NQ;
    const float2* __restrict__ r = R + (size_t)b * NR;

    const int clen = (NR + RC - 1) / RC;
    const int rbeg = rc * clen;
    const int rend = (rbeg + clen < NR) ? (rbeg + clen) : NR;
    if (rbeg >= rend) return;

    int   qi[TM];
    float n2x[TM], n2y[TM], qn[TM];
    f32x2 mnv[TM];
#pragma unroll
    for (int k = 0; k < TM; ++k) {
        qi[k] = blockIdx.x * (BLK * TM) + k * BLK + (int)threadIdx.x;
        int idx = qi[k] < NQ ? qi[k] : NQ - 1;
        float2 p = q[idx];
        n2x[k] = -2.0f * p.x;
        n2y[k] = -2.0f * p.y;
        qn[k]  = fmaf(p.y, p.y, p.x * p.x);
        mnv[k] = (f32x2)(3.0e38f);
    }

    int n = rbeg;
    // align to even float2 index so float4 loads are 16B-aligned
    for (; n < rend && (n & 1); ++n) {
        float2 p = r[n];
        float va = fmaf(p.y, p.y, p.x * p.x);
#pragma unroll
        for (int k = 0; k < TM; ++k) {
            float v = fmaf(n2x[k], p.x, fmaf(n2y[k], p.y, va));
            mnv[k].x = fminf(mnv[k].x, v);
        }
    }

    // main: 8 refs per iteration = 4 packed groups of 2
    for (; n + 8 <= rend; n += 8) {
        f32x2 px[4], py[4], va[4];
#pragma unroll
        for (int g = 0; g < 4; ++g) {
            float4 p4 = *(const float4*)&r[n + 2 * g];   // wave-uniform
            px[g] = (f32x2){p4.x, p4.z};
            py[g] = (f32x2){p4.y, p4.w};
            va[g] = __builtin_elementwise_fma(py[g], py[g], px[g] * px[g]);
        }
#pragma unroll
        for (int k = 0; k < TM; ++k) {
            f32x2 cx = (f32x2)(n2x[k]);
            f32x2 cy = (f32x2)(n2y[k]);
            f32x2 v0 = __builtin_elementwise_fma(cx, px[0],
                        __builtin_elementwise_fma(cy, py[0], va[0]));
            f32x2 v1 = __builtin_elementwise_fma(cx, px[1],
                        __builtin_elementwise_fma(cy, py[1], va[1]));
            f32x2 v2 = __builtin_elementwise_fma(cx, px[2],
                        __builtin_elementwise_fma(cy, py[2], va[2]));
            f32x2 v3 = __builtin_elementwise_fma(cx, px[3],
                        __builtin_elementwise_fma(cy, py[3], va[3]));
            f32x2 m01 = __builtin_elementwise_min(v0, v1);
            f32x2 m23 = __builtin_elementwise_min(v2, v3);
            mnv[k] = __builtin_elementwise_min(mnv[k],
                        __builtin_elementwise_min(m01, m23));
        }
    }

    // tail
    for (; n < rend; ++n) {
        float2 p = r[n];
        float va = fmaf(p.y, p.y, p.x * p.x);
#pragma unroll
        for (int k = 0; k < TM; ++k) {
            float v = fmaf(n2x[k], p.x, fmaf(n2y[k], p.y, va));
            mnv[k].x = fminf(mnv[k].x, v);
        }
    }

#pragma unroll
    for (int k = 0; k < TM; ++k) {
        if (qi[k] < NQ) {
            float m = fminf(mnv[k].x, mnv[k].y);
            float d2 = fmaxf(m + qn[k], 0.0f);
            atomicMin(&o[qi[k]], __float_as_uint(d2));
        }
    }
}

__global__ __launch_bounds__(256) void chamfer_sqrt(
    unsigned int* __restrict__ io, int n)
{
    int i = blockIdx.x * 256 + threadIdx.x;
    if (i < n) {
        float d2 = __uint_as_float(io[i]);
        ((float*)io)[i] = sqrtf(d2);
    }
}

extern "C" void kernel_launch(void* const* d_in, const int* in_sizes, int n_in,
                              void* d_out, int out_size, void* d_ws, size_t ws_size,
                              hipStream_t stream) {
    const float2* tpts = (const float2*)d_in[0];
    const float2* apts = (const float2*)d_in[1];
    unsigned int* out = (unsigned int*)d_out;

    const int B = 16;
    const int M = in_sizes[0] / (B * 2);
    const int N = in_sizes[1] / (B * 2);
    const int total = B * (M + N);

    chamfer_init<<<(total + 255) / 256, 256, 0, stream>>>(out, total);

    const int maxQ = M > N ? M : N;
    dim3 grid((maxQ + BLK * TM - 1) / (BLK * TM), B, 2 * RC);
    chamfer_partial<<<grid, dim3(BLK), 0, stream>>>(tpts, apts, out, M, N, B);

    chamfer_sqrt<<<(total + 255) / 256, 256, 0, stream>>>(out, total);
}

// Round 5
// 40.658 us; speedup vs baseline: 3.3441x; 1.0665x over previous
//
#include <hip/hip_runtime.h>
#include <math.h>

// ChamferLoss: target [B,M,2] f32, actual [B,N,2] f32
// out = concat(forward[B,M], backward[B,N]) f32
//
// Round 5: v_min3_f32 (inline asm) for the min reduction — CDNA has NO
// v_pk_min_f32, so round 4's packed min scalarized. Now per 8 refs per
// query: 8 v_pk_fma_f32 + 4 v_min3_f32 = 1.5 inst/pair.
// Partial minima over RC=32 ref chunks, combined via atomicMin on
// uint-encoded d^2 (order-preserving for non-negative floats).

typedef float f32x2 __attribute__((ext_vector_type(2)));

#define BLK 256
#define TM  8     // queries per thread
#define RC  32    // reference chunks per (b,dir)

__device__ __forceinline__ float min3f(float a, float b, float c) {
    float d;
    asm("v_min3_f32 %0, %1, %2, %3" : "=v"(d) : "v"(a), "v"(b), "v"(c));
    return d;
}

__global__ __launch_bounds__(256) void chamfer_init(unsigned int* __restrict__ out, int n) {
    int i = blockIdx.x * 256 + threadIdx.x;
    if (i < n) out[i] = 0x7F800000u;  // +inf
}

__global__ __launch_bounds__(BLK) void chamfer_partial(
    const float2* __restrict__ tpts,   // [B, M]
    const float2* __restrict__ apts,   // [B, N]
    unsigned int* __restrict__ out,    // [B*M + B*N], d^2 as uint bits
    int M, int N, int B)
{
    const int b   = blockIdx.y;
    const int zc  = blockIdx.z;
    const int dir = zc & 1;       // 0: forward (queries=target), 1: backward
    const int rc  = zc >> 1;      // which reference chunk

    const float2* __restrict__ Q = dir ? apts : tpts;
    const float2* __restrict__ R = dir ? tpts : apts;
    const int NQ = dir ? N : M;
    const int NR = dir ? M : N;
    unsigned int* __restrict__ o =
        out + (dir ? ((size_t)B * M + (size_t)b * N) : ((size_t)b * M));

    const float2* __restrict__ q = Q + (size_t)b * NQ;
    const float2* __restrict__ r = R + (size_t)b * NR;

    const int clen = (NR + RC - 1) / RC;
    const int rbeg = rc * clen;
    const int rend = (rbeg + clen < NR) ? (rbeg + clen) : NR;
    if (rbeg >= rend) return;

    int   qi[TM];
    float n2x[TM], n2y[TM], qn[TM], mn[TM];
#pragma unroll
    for (int k = 0; k < TM; ++k) {
        qi[k] = blockIdx.x * (BLK * TM) + k * BLK + (int)threadIdx.x;
        int idx = qi[k] < NQ ? qi[k] : NQ - 1;
        float2 p = q[idx];
        n2x[k] = -2.0f * p.x;
        n2y[k] = -2.0f * p.y;
        qn[k]  = fmaf(p.y, p.y, p.x * p.x);
        mn[k]  = 3.0e38f;
    }

    int n = rbeg;
    // align to even float2 index so float4 loads are 16B-aligned
    for (; n < rend && (n & 1); ++n) {
        float2 p = r[n];
        float va = fmaf(p.y, p.y, p.x * p.x);
#pragma unroll
        for (int k = 0; k < TM; ++k) {
            float v = fmaf(n2x[k], p.x, fmaf(n2y[k], p.y, va));
            mn[k] = fminf(mn[k], v);
        }
    }

    // main: 8 refs per iteration = 4 packed groups of 2
    for (; n + 8 <= rend; n += 8) {
        f32x2 px[4], py[4], va[4];
#pragma unroll
        for (int g = 0; g < 4; ++g) {
            float4 p4 = *(const float4*)&r[n + 2 * g];   // wave-uniform
            px[g] = (f32x2){p4.x, p4.z};
            py[g] = (f32x2){p4.y, p4.w};
            va[g] = __builtin_elementwise_fma(py[g], py[g], px[g] * px[g]);
        }
#pragma unroll
        for (int k = 0; k < TM; ++k) {
            f32x2 cx = (f32x2)(n2x[k]);
            f32x2 cy = (f32x2)(n2y[k]);
            f32x2 v0 = __builtin_elementwise_fma(cx, px[0],
                        __builtin_elementwise_fma(cy, py[0], va[0]));
            f32x2 v1 = __builtin_elementwise_fma(cx, px[1],
                        __builtin_elementwise_fma(cy, py[1], va[1]));
            f32x2 v2 = __builtin_elementwise_fma(cx, px[2],
                        __builtin_elementwise_fma(cy, py[2], va[2]));
            f32x2 v3 = __builtin_elementwise_fma(cx, px[3],
                        __builtin_elementwise_fma(cy, py[3], va[3]));
            float m = min3f(v0.x, v0.y, v1.x);
            m       = min3f(m, v1.y, v2.x);
            m       = min3f(m, v2.y, v3.x);
            mn[k]   = min3f(m, v3.y, mn[k]);
        }
    }

    // tail
    for (; n < rend; ++n) {
        float2 p = r[n];
        float va = fmaf(p.y, p.y, p.x * p.x);
#pragma unroll
        for (int k = 0; k < TM; ++k) {
            float v = fmaf(n2x[k], p.x, fmaf(n2y[k], p.y, va));
            mn[k] = fminf(mn[k], v);
        }
    }

#pragma unroll
    for (int k = 0; k < TM; ++k) {
        if (qi[k] < NQ) {
            float d2 = fmaxf(mn[k] + qn[k], 0.0f);
            atomicMin(&o[qi[k]], __float_as_uint(d2));
        }
    }
}

__global__ __launch_bounds__(256) void chamfer_sqrt(
    unsigned int* __restrict__ io, int n)
{
    int i = blockIdx.x * 256 + threadIdx.x;
    if (i < n) {
        float d2 = __uint_as_float(io[i]);
        ((float*)io)[i] = sqrtf(d2);
    }
}

extern "C" void kernel_launch(void* const* d_in, const int* in_sizes, int n_in,
                              void* d_out, int out_size, void* d_ws, size_t ws_size,
                              hipStream_t stream) {
    const float2* tpts = (const float2*)d_in[0];
    const float2* apts = (const float2*)d_in[1];
    unsigned int* out = (unsigned int*)d_out;

    const int B = 16;
    const int M = in_sizes[0] / (B * 2);
    const int N = in_sizes[1] / (B * 2);
    const int total = B * (M + N);

    chamfer_init<<<(total + 255) / 256, 256, 0, stream>>>(out, total);

    const int maxQ = M > N ? M : N;
    dim3 grid((maxQ + BLK * TM - 1) / (BLK * TM), B, 2 * RC);
    chamfer_partial<<<grid, dim3(BLK), 0, stream>>>(tpts, apts, out, M, N, B);

    chamfer_sqrt<<<(total + 255) / 256, 256, 0, stream>>>(out, total);
}